// Round 7
// baseline (425.196 us; speedup 1.0000x reference)
//
#include <hip/hip_runtime.h>
#include <hip/hip_fp16.h>
#include <math.h>

#define NEG_SLOPE 0.2f

// ---- bucket CSR parameters: 128-node buckets (s packs in 16b since N<65536,
//      dlocal in 7b -> 4-byte pair entries) ----
#define DSHIFT 7
#define DSZ 128
#define NBUCK_MAX 512
#define PART_BLOCKS 256

typedef __attribute__((ext_vector_type(8))) _Float16 v8h;
typedef __attribute__((ext_vector_type(4))) float v4f;

__device__ __forceinline__ int ntload_i(const int* p) {
    return __builtin_nontemporal_load(p);
}

// ---------------------------------------------------------------------------
// xcast: x fp32 -> fp16. Also zeroes the bucket-count array each launch
// (replay safety under graph re-execution).
// ---------------------------------------------------------------------------
__global__ __launch_bounds__(256)
void xcast_kernel(const float* __restrict__ x, _Float16* __restrict__ xh,
                  int total4, int* __restrict__ bcount) {
    int i = blockIdx.x * blockDim.x + threadIdx.x;
    if (i < NBUCK_MAX) bcount[i] = 0;
    if (i >= total4) return;
    float4 v = ((const float4*)x)[i];
    _Float16 o[4] = {(_Float16)v.x, (_Float16)v.y, (_Float16)v.z, (_Float16)v.w};
    ((uint2*)xh)[i] = *(const uint2*)o;
}

// ---------------------------------------------------------------------------
// CSR build (R16 structure, proven): LDS-counted bucket sort, exact windows,
// 4B packed pairs.
// ---------------------------------------------------------------------------
__global__ __launch_bounds__(256)
void part_count_kernel(const int* __restrict__ ei, int E, int n, int nbuck,
                       int* __restrict__ bcount) {
    __shared__ int cnt[NBUCK_MAX];
    int t = threadIdx.x;
    for (int k = t; k < nbuck; k += 256) cnt[k] = 0;
    __syncthreads();
    int Etot = E + n;
    int chunk = (Etot + gridDim.x - 1) / gridDim.x;
    int s0 = blockIdx.x * chunk;
    int s1 = min(Etot, s0 + chunk);
    for (int i = s0 + t; i < s1; i += 256) {
        int d = (i < E) ? ntload_i(ei + E + i) : (i - E);
        if ((unsigned)d < (unsigned)n) atomicAdd(&cnt[d >> DSHIFT], 1);
    }
    __syncthreads();
    for (int k = t; k < nbuck; k += 256) {
        int c = cnt[k];
        if (c) atomicAdd(&bcount[k], c);
    }
}

__global__ void bucket_scan_kernel(const int* __restrict__ bcount,
                                   int* __restrict__ colbase,
                                   int* __restrict__ pcur,
                                   int* __restrict__ rptr,
                                   int n, int nbuck) {
    __shared__ int sm[512];
    int t = threadIdx.x;
    int v = (t < nbuck) ? bcount[t] : 0;
    sm[t] = v;
    __syncthreads();
    int x = v;
    for (int off = 1; off < 512; off <<= 1) {
        int y = (t >= off) ? sm[t - off] : 0;
        __syncthreads();
        x += y;
        sm[t] = x;
        __syncthreads();
    }
    if (t < nbuck) { colbase[t] = x - v; pcur[t] = x - v; }
    if (t == nbuck - 1) rptr[n] = x;
}

__global__ __launch_bounds__(256)
void part_write_kernel(const int* __restrict__ ei, int E, int n, int nbuck,
                       int* __restrict__ pcur,
                       unsigned* __restrict__ pairs) {
    __shared__ int cnt[NBUCK_MAX];
    __shared__ int lcur[NBUCK_MAX];
    int t = threadIdx.x;
    for (int k = t; k < nbuck; k += 256) cnt[k] = 0;
    __syncthreads();
    int Etot = E + n;
    int chunk = (Etot + gridDim.x - 1) / gridDim.x;
    int s0 = blockIdx.x * chunk;
    int s1 = min(Etot, s0 + chunk);
    for (int i = s0 + t; i < s1; i += 256) {
        int d = (i < E) ? ntload_i(ei + E + i) : (i - E);
        if ((unsigned)d < (unsigned)n) atomicAdd(&cnt[d >> DSHIFT], 1);
    }
    __syncthreads();
    for (int k = t; k < nbuck; k += 256) {
        int c = cnt[k];
        if (c) lcur[k] = atomicAdd(&pcur[k], c);
    }
    __syncthreads();
    for (int i = s0 + t; i < s1; i += 256) {
        int s, d;
        if (i < E) { s = ntload_i(ei + i); d = ntload_i(ei + E + i); }
        else       { s = d = i - E; }
        if ((unsigned)d < (unsigned)n) {
            if ((unsigned)s >= (unsigned)n) s = 0;   // defensive clamp
            int pos = atomicAdd(&lcur[d >> DSHIFT], 1);
            pairs[pos] = (unsigned)s | ((unsigned)(d & (DSZ - 1)) << 16);
        }
    }
}

__global__ __launch_bounds__(256)
void fine_kernel(const unsigned* __restrict__ pairs,
                 const int* __restrict__ colbase,
                 const int* __restrict__ bcount,
                 int* __restrict__ rptr,
                 int* __restrict__ col, int n) {
    __shared__ int cnt[DSZ];
    __shared__ int ofs[DSZ];
    int b = blockIdx.x, t = threadIdx.x;
    int p0 = colbase[b], p1 = p0 + bcount[b];
    if (t < DSZ) cnt[t] = 0;
    __syncthreads();
    for (int i = p0 + t; i < p1; i += 256)
        atomicAdd(&cnt[pairs[i] >> 16], 1);
    __syncthreads();
    int v = (t < DSZ) ? cnt[t] : 0;
    if (t < DSZ) ofs[t] = v;
    __syncthreads();
    int x = v;
    for (int off = 1; off < DSZ; off <<= 1) {
        int y = (t >= off && t < DSZ) ? ofs[t - off] : 0;
        __syncthreads();
        if (t < DSZ) { x += y; ofs[t] = x; }
        __syncthreads();
    }
    int d0 = b << DSHIFT;
    if (t < DSZ) {
        int start = p0 + x - v;
        if (d0 + t < n) rptr[d0 + t] = start;
        cnt[t] = start;   // reuse as cursor
    }
    __syncthreads();
    for (int i = p0 + t; i < p1; i += 256) {
        unsigned u = pairs[i];
        int pos = atomicAdd(&cnt[u >> 16], 1);
        col[pos] = (int)(u & 0xFFFFu);
    }
}

// ---------------------------------------------------------------------------
// prep: build B-fragments for all three MFMA transforms (unchanged).
// ---------------------------------------------------------------------------
__global__ void prep_kernel(const float* __restrict__ cW1, const float* __restrict__ rW1,
                            const float* __restrict__ cas1, const float* __restrict__ cad1,
                            const float* __restrict__ ras1, const float* __restrict__ rad1,
                            const float* __restrict__ cW2, const float* __restrict__ rW2,
                            const float* __restrict__ cas2, const float* __restrict__ cad2,
                            const float* __restrict__ ras2, const float* __restrict__ rad2,
                            const float* __restrict__ clW, const float* __restrict__ rlW,
                            _Float16* __restrict__ WB1,
                            _Float16* __restrict__ WB2,
                            _Float16* __restrict__ WBh) {
    __shared__ float f1s[2][64], f1d[2][64];
    __shared__ float f2s[2][32], f2d[2][32];
    int t = threadIdx.x;
    if (t < 128) {
        int b = t >> 6, k = t & 63;
        const float* W   = b ? rW1 : cW1;
        const float* as_ = b ? ras1 : cas1;
        const float* ad_ = b ? rad1 : cad1;
        float s1 = 0.f, s2 = 0.f;
        for (int f = 0; f < 32; ++f) {
            s1 = fmaf(W[k * 32 + f], as_[f], s1);
            s2 = fmaf(W[k * 32 + f], ad_[f], s2);
        }
        f1s[b][k] = s1;
        f1d[b][k] = s2;
    } else if (t < 192) {
        int b = (t - 128) >> 5, k = (t - 128) & 31;
        const float* W   = b ? rW2 : cW2;
        const float* as_ = b ? ras2 : cas2;
        const float* ad_ = b ? rad2 : cad2;
        float s1 = 0.f, s2 = 0.f;
        for (int f = 0; f < 32; ++f) {
            s1 = fmaf(W[k * 32 + f], as_[f], s1);
            s2 = fmaf(W[k * 32 + f], ad_[f], s2);
        }
        f2s[b][k] = s1;
        f2d[b][k] = s2;
    }
    __syncthreads();
    for (int idx = t; idx < 6144; idx += 256) {   // WB1
        int blk = idx >> 9;
        int l = (idx >> 3) & 63, j = idx & 7;
        int b = blk / 6, rem = blk % 6, c = rem / 3, tt = rem % 3;
        int k = c * 32 + (l >> 4) * 8 + j;
        int nn = l & 15;
        const float* W = b ? rW1 : cW1;
        float v;
        if (tt < 2) v = W[k * 32 + tt * 16 + nn];
        else v = (nn == 0) ? f1s[b][k] : ((nn == 1) ? f1d[b][k] : 0.f);
        WB1[idx] = (_Float16)v;
    }
    for (int idx = t; idx < 3072; idx += 256) {   // WB2
        int blk = idx >> 9;
        int l = (idx >> 3) & 63, j = idx & 7;
        int b = blk / 3, tt = blk % 3;
        int k = (l >> 4) * 8 + j;
        int nn = l & 15;
        const float* W = b ? rW2 : cW2;
        float v;
        if (tt < 2) v = W[k * 32 + tt * 16 + nn];
        else v = (nn == 0) ? f2s[b][k] : ((nn == 1) ? f2d[b][k] : 0.f);
        WB2[idx] = (_Float16)v;
    }
    for (int idx = t; idx < 2048; idx += 256) {   // WBh
        int blk = idx >> 9;
        int l = (idx >> 3) & 63, j = idx & 7;
        int b = blk >> 1, tt = blk & 1;
        int k = (l >> 4) * 8 + j;
        int nn = l & 15;
        const float* W = b ? rlW : clW;
        WBh[idx] = (_Float16)W[k * 32 + tt * 16 + nn];
    }
}

// ---------------------------------------------------------------------------
// t1 via MFMA (R13, proven): one wave per 16-node tile; 12 MFMA. Writes
// interleaved h rows (half2(C,R), 128B/row -> adjacent-line gather in agg).
// ---------------------------------------------------------------------------
__global__ __launch_bounds__(256)
void t1_mfma_kernel(const _Float16* __restrict__ xh,
                    const _Float16* __restrict__ WB1,
                    __half2* __restrict__ h,
                    float2* __restrict__ es2,
                    float2* __restrict__ ed2, int n) {
    int wave = (blockIdx.x * blockDim.x + threadIdx.x) >> 6;
    int lane = threadIdx.x & 63;
    int ntiles = n >> 4;
    if (wave >= ntiles) return;
    int m0 = wave << 4;
    int quad = lane >> 4, nn = lane & 15;
    const _Float16* arow = xh + (size_t)(m0 + nn) * 64 + quad * 8;
    v8h a0 = *(const v8h*)arow;
    v8h a1 = *(const v8h*)(arow + 32);
    v4f acc[2][3];
#pragma unroll
    for (int b = 0; b < 2; ++b)
#pragma unroll
        for (int tt = 0; tt < 3; ++tt) acc[b][tt] = (v4f){0.f, 0.f, 0.f, 0.f};
#pragma unroll
    for (int b = 0; b < 2; ++b) {
#pragma unroll
        for (int c = 0; c < 2; ++c) {
            v8h av = c ? a1 : a0;
#pragma unroll
            for (int tt = 0; tt < 3; ++tt) {
                v8h wb = *(const v8h*)(WB1 + (((b * 2 + c) * 3 + tt) << 9) + lane * 8);
                acc[b][tt] = __builtin_amdgcn_mfma_f32_16x16x32_f16(av, wb, acc[b][tt], 0, 0, 0);
            }
        }
    }
#pragma unroll
    for (int i = 0; i < 4; ++i) {
        int m = m0 + quad * 4 + i;
        h[(size_t)m * 32 + nn]      = __floats2half2_rn(acc[0][0][i], acc[1][0][i]);
        h[(size_t)m * 32 + 16 + nn] = __floats2half2_rn(acc[0][1][i], acc[1][1][i]);
        if (nn == 0) es2[m] = make_float2(acc[0][2][i], acc[1][2][i]);
        if (nn == 1) ed2[m] = make_float2(acc[0][2][i], acc[1][2][i]);
    }
}

// ---------------------------------------------------------------------------
// A-fragment builder from fused half2 rows (proven).
// ---------------------------------------------------------------------------
__device__ __forceinline__ void load_a_frag(const __half2* __restrict__ g,
                                            int m0, int nn, int quad,
                                            v8h& aC, v8h& aR) {
    const uint4* gp = (const uint4*)(g + (size_t)(m0 + nn) * 32 + quad * 8);
    uint4 q0 = gp[0], q1 = gp[1];
    unsigned short buf[16];
    *(uint4*)buf = q0;
    *(uint4*)(buf + 8) = q1;
#pragma unroll
    for (int i = 0; i < 8; ++i) {
        ((unsigned short*)&aC)[i] = buf[2 * i];
        ((unsigned short*)&aR)[i] = buf[2 * i + 1];
    }
}

// ---------------------------------------------------------------------------
// t2 via MFMA (proven).
// ---------------------------------------------------------------------------
__global__ __launch_bounds__(256)
void t2_mfma_kernel(const __half2* __restrict__ g1,
                    const _Float16* __restrict__ WB2,
                    __half2* __restrict__ h2,
                    float2* __restrict__ es2o,
                    float2* __restrict__ ed2o, int n) {
    int wave = (blockIdx.x * blockDim.x + threadIdx.x) >> 6;
    int lane = threadIdx.x & 63;
    if (wave >= (n >> 4)) return;
    int m0 = wave << 4;
    int quad = lane >> 4, nn = lane & 15;
    v8h aC, aR;
    load_a_frag(g1, m0, nn, quad, aC, aR);
    v4f acc[2][3];
#pragma unroll
    for (int b = 0; b < 2; ++b)
#pragma unroll
        for (int tt = 0; tt < 3; ++tt) acc[b][tt] = (v4f){0.f, 0.f, 0.f, 0.f};
#pragma unroll
    for (int b = 0; b < 2; ++b) {
        v8h av = b ? aR : aC;
#pragma unroll
        for (int tt = 0; tt < 3; ++tt) {
            v8h wb = *(const v8h*)(WB2 + ((b * 3 + tt) << 9) + lane * 8);
            acc[b][tt] = __builtin_amdgcn_mfma_f32_16x16x32_f16(av, wb, acc[b][tt], 0, 0, 0);
        }
    }
#pragma unroll
    for (int i = 0; i < 4; ++i) {
        int m = m0 + quad * 4 + i;
        h2[(size_t)m * 32 + nn]      = __floats2half2_rn(acc[0][0][i], acc[1][0][i]);
        h2[(size_t)m * 32 + 16 + nn] = __floats2half2_rn(acc[0][1][i], acc[1][1][i]);
        if (nn == 0) es2o[m] = make_float2(acc[0][2][i], acc[1][2][i]);
        if (nn == 1) ed2o[m] = make_float2(acc[0][2][i], acc[1][2][i]);
    }
}

// ---------------------------------------------------------------------------
// head via MFMA (proven).
// ---------------------------------------------------------------------------
__global__ __launch_bounds__(256)
void head_mfma_kernel(const __half2* __restrict__ g2,
                      const _Float16* __restrict__ WBh,
                      const float* __restrict__ clb,
                      const float* __restrict__ rlb,
                      float* __restrict__ out, int n) {
    int wave = (blockIdx.x * blockDim.x + threadIdx.x) >> 6;
    int lane = threadIdx.x & 63;
    if (wave >= (n >> 4)) return;
    int m0 = wave << 4;
    int quad = lane >> 4, nn = lane & 15;
    v8h aC, aR;
    load_a_frag(g2, m0, nn, quad, aC, aR);
    v4f acc[2][2];
#pragma unroll
    for (int b = 0; b < 2; ++b)
#pragma unroll
        for (int tt = 0; tt < 2; ++tt) acc[b][tt] = (v4f){0.f, 0.f, 0.f, 0.f};
#pragma unroll
    for (int b = 0; b < 2; ++b) {
        v8h av = b ? aR : aC;
#pragma unroll
        for (int tt = 0; tt < 2; ++tt) {
            v8h wb = *(const v8h*)(WBh + ((b * 2 + tt) << 9) + lane * 8);
            acc[b][tt] = __builtin_amdgcn_mfma_f32_16x16x32_f16(av, wb, acc[b][tt], 0, 0, 0);
        }
    }
    float lb0c = clb[nn], lb1c = clb[16 + nn];
    float lb0r = rlb[nn], lb1r = rlb[16 + nn];
#pragma unroll
    for (int i = 0; i < 4; ++i) {
        int m = m0 + quad * 4 + i;
        float y0 = acc[0][0][i] + lb0c;
        float y1 = acc[0][1][i] + lb1c;
        out[(size_t)m * 32 + nn]      = 1.f / (1.f + __expf(-y0));
        out[(size_t)m * 32 + 16 + nn] = 1.f / (1.f + __expf(-y1));
        out[(size_t)n * 32 + (size_t)m * 32 + nn]      = acc[1][0][i] + lb0r;
        out[(size_t)n * 32 + (size_t)m * 32 + 16 + nn] = acc[1][1][i] + lb1r;
    }
}

// ---------------------------------------------------------------------------
// Aggregation (R2 core + R20 scheduling): persistent grid (2048 blocks,
// grid-stride over dst groups -> no 3-round tail) and unroll 4 (deeper
// miss-level parallelism against ~600-900cy L3 latency). Math/order
// byte-identical to R2.
// ---------------------------------------------------------------------------
__global__ __launch_bounds__(256, 8)
void agg_kernel(const int* __restrict__ rptr,
                const int* __restrict__ col,
                const __half2* __restrict__ h,
                const float2* __restrict__ es2,
                const float2* __restrict__ ed2,
                const float* __restrict__ bc,
                const float* __restrict__ br,
                __half2* __restrict__ gout, int n) {
    int lane = threadIdx.x & 31;
    int sub = lane >> 2;     // edge slot 0..7
    int fq  = lane & 3;      // feature octet 0..3
    int grp0 = (blockIdx.x * blockDim.x + threadIdx.x) >> 5;
    int gstr = (gridDim.x * blockDim.x) >> 5;
    for (int d = grp0; d < n; d += gstr) {
        int beg = rptr[d], end = rptr[d + 1];
        float2 edv = ed2[d];
        float accC[8], accR[8];
#pragma unroll
        for (int i = 0; i < 8; ++i) { accC[i] = 0.f; accR[i] = 0.f; }
        float lc = 0.f, lr = 0.f;
#pragma unroll 4
        for (int base = beg; base + sub < end; base += 8) {
            int e = base + sub;
            int s = ntload_i(col + e);
            float2 ev = es2[s];
            float tc = ev.x + edv.x, tr = ev.y + edv.y;
            tc = (tc > 0.f) ? tc : NEG_SLOPE * tc;
            tr = (tr > 0.f) ? tr : NEG_SLOPE * tr;
            float exc = __expf(tc), exr = __expf(tr);
            lc += exc; lr += exr;
            const uint4* rp = (const uint4*)(h + ((size_t)s << 5));
            uint4 q0 = rp[2 * fq];
            uint4 q1 = rp[2 * fq + 1];
            const __half2* hp0 = (const __half2*)&q0;
            const __half2* hp1 = (const __half2*)&q1;
#pragma unroll
            for (int i = 0; i < 4; ++i) {
                float2 v0 = __half22float2(hp0[i]);
                float2 v1 = __half22float2(hp1[i]);
                accC[i]     = fmaf(v0.x, exc, accC[i]);
                accR[i]     = fmaf(v0.y, exr, accR[i]);
                accC[4 + i] = fmaf(v1.x, exc, accC[4 + i]);
                accR[4 + i] = fmaf(v1.y, exr, accR[4 + i]);
            }
        }
#pragma unroll
        for (int off = 4; off <= 16; off <<= 1) {
            lc += __shfl_xor(lc, off, 32);
            lr += __shfl_xor(lr, off, 32);
#pragma unroll
            for (int i = 0; i < 8; ++i) {
                accC[i] += __shfl_xor(accC[i], off, 32);
                accR[i] += __shfl_xor(accR[i], off, 32);
            }
        }
        if (sub == 0) {
            float ilc = 1.f / lc, ilr = 1.f / lr;
            __half2 o[8];
#pragma unroll
            for (int i = 0; i < 8; ++i) {
                float gc = fmaxf(accC[i] * ilc + bc[fq * 8 + i], 0.f);
                float gr = fmaxf(accR[i] * ilr + br[fq * 8 + i], 0.f);
                o[i] = __floats2half2_rn(gc, gr);
            }
            uint4* dst = (uint4*)(gout + ((size_t)d << 5) + fq * 8);
            dst[0] = *(const uint4*)&o[0];
            dst[1] = *(const uint4*)&o[4];
        }
    }
}

// ---------------------------------------------------------------------------
// Launch
// ---------------------------------------------------------------------------
extern "C" void kernel_launch(void* const* d_in, const int* in_sizes, int n_in,
                              void* d_out, int out_size, void* d_ws, size_t ws_size,
                              hipStream_t stream) {
    const float* x = (const float*)d_in[0];
    const int* ei = (const int*)d_in[1];   // int32; [src(E), dst(E)]
    const int N = in_sizes[0] / 64;
    const int E = in_sizes[1] / 2;
    const int Etot = E + N;

    const float* cW1  = (const float*)d_in[2];
    const float* cas1 = (const float*)d_in[3];
    const float* cad1 = (const float*)d_in[4];
    const float* cb1  = (const float*)d_in[5];
    const float* cW2  = (const float*)d_in[6];
    const float* cas2 = (const float*)d_in[7];
    const float* cad2 = (const float*)d_in[8];
    const float* cb2  = (const float*)d_in[9];
    const float* clW  = (const float*)d_in[10];
    const float* clb  = (const float*)d_in[11];
    const float* rW1  = (const float*)d_in[12];
    const float* ras1 = (const float*)d_in[13];
    const float* rad1 = (const float*)d_in[14];
    const float* rb1  = (const float*)d_in[15];
    const float* rW2  = (const float*)d_in[16];
    const float* ras2 = (const float*)d_in[17];
    const float* rad2 = (const float*)d_in[18];
    const float* rb2  = (const float*)d_in[19];
    const float* rlW  = (const float*)d_in[20];
    const float* rlb  = (const float*)d_in[21];

    const int nbuck = (N + DSZ - 1) >> DSHIFT;   // 391 for N=50000 (<=512)

    char* w = (char*)d_ws;
    size_t off = 0;
    auto alloc = [&](size_t bytes) {
        void* p = w + off;
        off = (off + bytes + 255) & ~(size_t)255;
        return p;
    };
    int*       rptr    = (int*)alloc((size_t)(N + 1) * 4);
    int*       bcount  = (int*)alloc(NBUCK_MAX * 4);
    int*       colbase = (int*)alloc(NBUCK_MAX * 4);
    int*       pcur    = (int*)alloc(NBUCK_MAX * 4);
    int*       col     = (int*)alloc((size_t)Etot * 4);
    unsigned*  pairs   = (unsigned*)alloc((size_t)Etot * 4);   // 6.8 MB packed
    __half2*   h       = (__half2*)alloc((size_t)N * 32 * 4);  // h1, reused as h2
    __half2*   g       = (__half2*)alloc((size_t)N * 32 * 4);  // g1, reused as g2
    float2*    esA     = (float2*)alloc((size_t)N * 8);
    float2*    edA     = (float2*)alloc((size_t)N * 8);
    float2*    esB     = (float2*)alloc((size_t)N * 8);
    float2*    edB     = (float2*)alloc((size_t)N * 8);
    _Float16*  xh      = (_Float16*)alloc((size_t)N * 64 * 2); // 6.4 MB
    _Float16*  WB1     = (_Float16*)alloc(6144 * 2);
    _Float16*  WB2     = (_Float16*)alloc(3072 * 2);
    _Float16*  WBh     = (_Float16*)alloc(2048 * 2);
    (void)ws_size;

    float* out = (float*)d_out;
    const int node_blocks = (N * 32 + 255) / 256;   // 32-lane groups (agg)
    const int agg_blocks  = (node_blocks < 2048) ? node_blocks : 2048;
    const int xc_blocks   = (N * 64 / 4 + 255) / 256;
    const int mfma_blocks = ((N >> 4) * 64 + 255) / 256;  // 1 wave / 16 nodes

    // ---- MFMA prep + CSR build ----
    xcast_kernel<<<xc_blocks, 256, 0, stream>>>(x, xh, N * 64 / 4, bcount);
    prep_kernel<<<1, 256, 0, stream>>>(cW1, rW1, cas1, cad1, ras1, rad1,
                                       cW2, rW2, cas2, cad2, ras2, rad2,
                                       clW, rlW, WB1, WB2, WBh);
    part_count_kernel<<<PART_BLOCKS, 256, 0, stream>>>(ei, E, N, nbuck, bcount);
    bucket_scan_kernel<<<1, 512, 0, stream>>>(bcount, colbase, pcur, rptr, N, nbuck);
    part_write_kernel<<<PART_BLOCKS, 256, 0, stream>>>(ei, E, N, nbuck, pcur, pairs);
    fine_kernel<<<nbuck, 256, 0, stream>>>(pairs, colbase, bcount, rptr, col, N);

    // ---- layer 1 ----
    t1_mfma_kernel<<<mfma_blocks, 256, 0, stream>>>(xh, WB1, h, esA, edA, N);
    agg_kernel<<<agg_blocks, 256, 0, stream>>>(
        rptr, col, h, esA, edA, cb1, rb1, g, N);

    // ---- layer 2 + heads ----
    t2_mfma_kernel<<<mfma_blocks, 256, 0, stream>>>(g, WB2, h, esB, edB, N);
    agg_kernel<<<agg_blocks, 256, 0, stream>>>(
        rptr, col, h, esB, edB, cb2, rb2, g, N);
    head_mfma_kernel<<<mfma_blocks, 256, 0, stream>>>(g, WBh, clb, rlb, out, N);
}

// Round 8
// 289.203 us; speedup vs baseline: 1.4702x; 1.4702x over previous
//
#include <hip/hip_runtime.h>
#include <hip/hip_fp16.h>
#include <math.h>

#define NEG_SLOPE 0.2f

// ---- bucket CSR parameters: 128-node buckets (s packs in 16b since N<65536,
//      dlocal in 7b -> 4-byte pair entries) ----
#define DSHIFT 7
#define DSZ 128
#define NBUCK_MAX 512
#define PART_BLOCKS 256

typedef __attribute__((ext_vector_type(8))) _Float16 v8h;
typedef __attribute__((ext_vector_type(4))) float v4f;

__device__ __forceinline__ int ntload_i(const int* p) {
    return __builtin_nontemporal_load(p);
}

// ---------------------------------------------------------------------------
// xcast: x fp32 -> fp16. Also zeroes the bucket-count array each launch
// (replay safety under graph re-execution).
// ---------------------------------------------------------------------------
__global__ __launch_bounds__(256)
void xcast_kernel(const float* __restrict__ x, _Float16* __restrict__ xh,
                  int total4, int* __restrict__ bcount) {
    int i = blockIdx.x * blockDim.x + threadIdx.x;
    if (i < NBUCK_MAX) bcount[i] = 0;
    if (i >= total4) return;
    float4 v = ((const float4*)x)[i];
    _Float16 o[4] = {(_Float16)v.x, (_Float16)v.y, (_Float16)v.z, (_Float16)v.w};
    ((uint2*)xh)[i] = *(const uint2*)o;
}

// ---------------------------------------------------------------------------
// CSR build (R16 structure, proven at 278.8): LDS-counted bucket sort, exact
// windows, 4B packed pairs.
// ---------------------------------------------------------------------------
__global__ __launch_bounds__(256)
void part_count_kernel(const int* __restrict__ ei, int E, int n, int nbuck,
                       int* __restrict__ bcount) {
    __shared__ int cnt[NBUCK_MAX];
    int t = threadIdx.x;
    for (int k = t; k < nbuck; k += 256) cnt[k] = 0;
    __syncthreads();
    int Etot = E + n;
    int chunk = (Etot + gridDim.x - 1) / gridDim.x;
    int s0 = blockIdx.x * chunk;
    int s1 = min(Etot, s0 + chunk);
    for (int i = s0 + t; i < s1; i += 256) {
        int d = (i < E) ? ntload_i(ei + E + i) : (i - E);
        if ((unsigned)d < (unsigned)n) atomicAdd(&cnt[d >> DSHIFT], 1);
    }
    __syncthreads();
    for (int k = t; k < nbuck; k += 256) {
        int c = cnt[k];
        if (c) atomicAdd(&bcount[k], c);
    }
}

__global__ void bucket_scan_kernel(const int* __restrict__ bcount,
                                   int* __restrict__ colbase,
                                   int* __restrict__ pcur,
                                   int* __restrict__ rptr,
                                   int n, int nbuck) {
    __shared__ int sm[512];
    int t = threadIdx.x;
    int v = (t < nbuck) ? bcount[t] : 0;
    sm[t] = v;
    __syncthreads();
    int x = v;
    for (int off = 1; off < 512; off <<= 1) {
        int y = (t >= off) ? sm[t - off] : 0;
        __syncthreads();
        x += y;
        sm[t] = x;
        __syncthreads();
    }
    if (t < nbuck) { colbase[t] = x - v; pcur[t] = x - v; }
    if (t == nbuck - 1) rptr[n] = x;
}

__global__ __launch_bounds__(256)
void part_write_kernel(const int* __restrict__ ei, int E, int n, int nbuck,
                       int* __restrict__ pcur,
                       unsigned* __restrict__ pairs) {
    __shared__ int cnt[NBUCK_MAX];
    __shared__ int lcur[NBUCK_MAX];
    int t = threadIdx.x;
    for (int k = t; k < nbuck; k += 256) cnt[k] = 0;
    __syncthreads();
    int Etot = E + n;
    int chunk = (Etot + gridDim.x - 1) / gridDim.x;
    int s0 = blockIdx.x * chunk;
    int s1 = min(Etot, s0 + chunk);
    for (int i = s0 + t; i < s1; i += 256) {
        int d = (i < E) ? ntload_i(ei + E + i) : (i - E);
        if ((unsigned)d < (unsigned)n) atomicAdd(&cnt[d >> DSHIFT], 1);
    }
    __syncthreads();
    for (int k = t; k < nbuck; k += 256) {
        int c = cnt[k];
        if (c) lcur[k] = atomicAdd(&pcur[k], c);
    }
    __syncthreads();
    for (int i = s0 + t; i < s1; i += 256) {
        int s, d;
        if (i < E) { s = ntload_i(ei + i); d = ntload_i(ei + E + i); }
        else       { s = d = i - E; }
        if ((unsigned)d < (unsigned)n) {
            if ((unsigned)s >= (unsigned)n) s = 0;   // defensive clamp
            int pos = atomicAdd(&lcur[d >> DSHIFT], 1);
            pairs[pos] = (unsigned)s | ((unsigned)(d & (DSZ - 1)) << 16);
        }
    }
}

__global__ __launch_bounds__(256)
void fine_kernel(const unsigned* __restrict__ pairs,
                 const int* __restrict__ colbase,
                 const int* __restrict__ bcount,
                 int* __restrict__ rptr,
                 int* __restrict__ col, int n) {
    __shared__ int cnt[DSZ];
    __shared__ int ofs[DSZ];
    int b = blockIdx.x, t = threadIdx.x;
    int p0 = colbase[b], p1 = p0 + bcount[b];
    if (t < DSZ) cnt[t] = 0;
    __syncthreads();
    for (int i = p0 + t; i < p1; i += 256)
        atomicAdd(&cnt[pairs[i] >> 16], 1);
    __syncthreads();
    int v = (t < DSZ) ? cnt[t] : 0;
    if (t < DSZ) ofs[t] = v;
    __syncthreads();
    int x = v;
    for (int off = 1; off < DSZ; off <<= 1) {
        int y = (t >= off && t < DSZ) ? ofs[t - off] : 0;
        __syncthreads();
        if (t < DSZ) { x += y; ofs[t] = x; }
        __syncthreads();
    }
    int d0 = b << DSHIFT;
    if (t < DSZ) {
        int start = p0 + x - v;
        if (d0 + t < n) rptr[d0 + t] = start;
        cnt[t] = start;   // reuse as cursor
    }
    __syncthreads();
    for (int i = p0 + t; i < p1; i += 256) {
        unsigned u = pairs[i];
        int pos = atomicAdd(&cnt[u >> 16], 1);
        col[pos] = (int)(u & 0xFFFFu);
    }
}

// ---------------------------------------------------------------------------
// prep: build B-fragments for all three MFMA transforms (unchanged).
// ---------------------------------------------------------------------------
__global__ void prep_kernel(const float* __restrict__ cW1, const float* __restrict__ rW1,
                            const float* __restrict__ cas1, const float* __restrict__ cad1,
                            const float* __restrict__ ras1, const float* __restrict__ rad1,
                            const float* __restrict__ cW2, const float* __restrict__ rW2,
                            const float* __restrict__ cas2, const float* __restrict__ cad2,
                            const float* __restrict__ ras2, const float* __restrict__ rad2,
                            const float* __restrict__ clW, const float* __restrict__ rlW,
                            _Float16* __restrict__ WB1,
                            _Float16* __restrict__ WB2,
                            _Float16* __restrict__ WBh) {
    __shared__ float f1s[2][64], f1d[2][64];
    __shared__ float f2s[2][32], f2d[2][32];
    int t = threadIdx.x;
    if (t < 128) {
        int b = t >> 6, k = t & 63;
        const float* W   = b ? rW1 : cW1;
        const float* as_ = b ? ras1 : cas1;
        const float* ad_ = b ? rad1 : cad1;
        float s1 = 0.f, s2 = 0.f;
        for (int f = 0; f < 32; ++f) {
            s1 = fmaf(W[k * 32 + f], as_[f], s1);
            s2 = fmaf(W[k * 32 + f], ad_[f], s2);
        }
        f1s[b][k] = s1;
        f1d[b][k] = s2;
    } else if (t < 192) {
        int b = (t - 128) >> 5, k = (t - 128) & 31;
        const float* W   = b ? rW2 : cW2;
        const float* as_ = b ? ras2 : cas2;
        const float* ad_ = b ? rad2 : cad2;
        float s1 = 0.f, s2 = 0.f;
        for (int f = 0; f < 32; ++f) {
            s1 = fmaf(W[k * 32 + f], as_[f], s1);
            s2 = fmaf(W[k * 32 + f], ad_[f], s2);
        }
        f2s[b][k] = s1;
        f2d[b][k] = s2;
    }
    __syncthreads();
    for (int idx = t; idx < 6144; idx += 256) {   // WB1
        int blk = idx >> 9;
        int l = (idx >> 3) & 63, j = idx & 7;
        int b = blk / 6, rem = blk % 6, c = rem / 3, tt = rem % 3;
        int k = c * 32 + (l >> 4) * 8 + j;
        int nn = l & 15;
        const float* W = b ? rW1 : cW1;
        float v;
        if (tt < 2) v = W[k * 32 + tt * 16 + nn];
        else v = (nn == 0) ? f1s[b][k] : ((nn == 1) ? f1d[b][k] : 0.f);
        WB1[idx] = (_Float16)v;
    }
    for (int idx = t; idx < 3072; idx += 256) {   // WB2
        int blk = idx >> 9;
        int l = (idx >> 3) & 63, j = idx & 7;
        int b = blk / 3, tt = blk % 3;
        int k = (l >> 4) * 8 + j;
        int nn = l & 15;
        const float* W = b ? rW2 : cW2;
        float v;
        if (tt < 2) v = W[k * 32 + tt * 16 + nn];
        else v = (nn == 0) ? f2s[b][k] : ((nn == 1) ? f2d[b][k] : 0.f);
        WB2[idx] = (_Float16)v;
    }
    for (int idx = t; idx < 2048; idx += 256) {   // WBh
        int blk = idx >> 9;
        int l = (idx >> 3) & 63, j = idx & 7;
        int b = blk >> 1, tt = blk & 1;
        int k = (l >> 4) * 8 + j;
        int nn = l & 15;
        const float* W = b ? rlW : clW;
        WBh[idx] = (_Float16)W[k * 32 + tt * 16 + nn];
    }
}

// ---------------------------------------------------------------------------
// t1 via MFMA (proven): one wave per 16-node tile; 12 MFMA. Writes
// interleaved h rows (half2(C,R), 128B/row -> adjacent-line gather in agg).
// ---------------------------------------------------------------------------
__global__ __launch_bounds__(256)
void t1_mfma_kernel(const _Float16* __restrict__ xh,
                    const _Float16* __restrict__ WB1,
                    __half2* __restrict__ h,
                    float2* __restrict__ es2,
                    float2* __restrict__ ed2, int n) {
    int wave = (blockIdx.x * blockDim.x + threadIdx.x) >> 6;
    int lane = threadIdx.x & 63;
    int ntiles = n >> 4;
    if (wave >= ntiles) return;
    int m0 = wave << 4;
    int quad = lane >> 4, nn = lane & 15;
    const _Float16* arow = xh + (size_t)(m0 + nn) * 64 + quad * 8;
    v8h a0 = *(const v8h*)arow;
    v8h a1 = *(const v8h*)(arow + 32);
    v4f acc[2][3];
#pragma unroll
    for (int b = 0; b < 2; ++b)
#pragma unroll
        for (int tt = 0; tt < 3; ++tt) acc[b][tt] = (v4f){0.f, 0.f, 0.f, 0.f};
#pragma unroll
    for (int b = 0; b < 2; ++b) {
#pragma unroll
        for (int c = 0; c < 2; ++c) {
            v8h av = c ? a1 : a0;
#pragma unroll
            for (int tt = 0; tt < 3; ++tt) {
                v8h wb = *(const v8h*)(WB1 + (((b * 2 + c) * 3 + tt) << 9) + lane * 8);
                acc[b][tt] = __builtin_amdgcn_mfma_f32_16x16x32_f16(av, wb, acc[b][tt], 0, 0, 0);
            }
        }
    }
#pragma unroll
    for (int i = 0; i < 4; ++i) {
        int m = m0 + quad * 4 + i;
        h[(size_t)m * 32 + nn]      = __floats2half2_rn(acc[0][0][i], acc[1][0][i]);
        h[(size_t)m * 32 + 16 + nn] = __floats2half2_rn(acc[0][1][i], acc[1][1][i]);
        if (nn == 0) es2[m] = make_float2(acc[0][2][i], acc[1][2][i]);
        if (nn == 1) ed2[m] = make_float2(acc[0][2][i], acc[1][2][i]);
    }
}

// ---------------------------------------------------------------------------
// A-fragment builder from fused half2 rows (proven).
// ---------------------------------------------------------------------------
__device__ __forceinline__ void load_a_frag(const __half2* __restrict__ g,
                                            int m0, int nn, int quad,
                                            v8h& aC, v8h& aR) {
    const uint4* gp = (const uint4*)(g + (size_t)(m0 + nn) * 32 + quad * 8);
    uint4 q0 = gp[0], q1 = gp[1];
    unsigned short buf[16];
    *(uint4*)buf = q0;
    *(uint4*)(buf + 8) = q1;
#pragma unroll
    for (int i = 0; i < 8; ++i) {
        ((unsigned short*)&aC)[i] = buf[2 * i];
        ((unsigned short*)&aR)[i] = buf[2 * i + 1];
    }
}

// ---------------------------------------------------------------------------
// t2 via MFMA (proven).
// ---------------------------------------------------------------------------
__global__ __launch_bounds__(256)
void t2_mfma_kernel(const __half2* __restrict__ g1,
                    const _Float16* __restrict__ WB2,
                    __half2* __restrict__ h2,
                    float2* __restrict__ es2o,
                    float2* __restrict__ ed2o, int n) {
    int wave = (blockIdx.x * blockDim.x + threadIdx.x) >> 6;
    int lane = threadIdx.x & 63;
    if (wave >= (n >> 4)) return;
    int m0 = wave << 4;
    int quad = lane >> 4, nn = lane & 15;
    v8h aC, aR;
    load_a_frag(g1, m0, nn, quad, aC, aR);
    v4f acc[2][3];
#pragma unroll
    for (int b = 0; b < 2; ++b)
#pragma unroll
        for (int tt = 0; tt < 3; ++tt) acc[b][tt] = (v4f){0.f, 0.f, 0.f, 0.f};
#pragma unroll
    for (int b = 0; b < 2; ++b) {
        v8h av = b ? aR : aC;
#pragma unroll
        for (int tt = 0; tt < 3; ++tt) {
            v8h wb = *(const v8h*)(WB2 + ((b * 3 + tt) << 9) + lane * 8);
            acc[b][tt] = __builtin_amdgcn_mfma_f32_16x16x32_f16(av, wb, acc[b][tt], 0, 0, 0);
        }
    }
#pragma unroll
    for (int i = 0; i < 4; ++i) {
        int m = m0 + quad * 4 + i;
        h2[(size_t)m * 32 + nn]      = __floats2half2_rn(acc[0][0][i], acc[1][0][i]);
        h2[(size_t)m * 32 + 16 + nn] = __floats2half2_rn(acc[0][1][i], acc[1][1][i]);
        if (nn == 0) es2o[m] = make_float2(acc[0][2][i], acc[1][2][i]);
        if (nn == 1) ed2o[m] = make_float2(acc[0][2][i], acc[1][2][i]);
    }
}

// ---------------------------------------------------------------------------
// head via MFMA (proven).
// ---------------------------------------------------------------------------
__global__ __launch_bounds__(256)
void head_mfma_kernel(const __half2* __restrict__ g2,
                      const _Float16* __restrict__ WBh,
                      const float* __restrict__ clb,
                      const float* __restrict__ rlb,
                      float* __restrict__ out, int n) {
    int wave = (blockIdx.x * blockDim.x + threadIdx.x) >> 6;
    int lane = threadIdx.x & 63;
    if (wave >= (n >> 4)) return;
    int m0 = wave << 4;
    int quad = lane >> 4, nn = lane & 15;
    v8h aC, aR;
    load_a_frag(g2, m0, nn, quad, aC, aR);
    v4f acc[2][2];
#pragma unroll
    for (int b = 0; b < 2; ++b)
#pragma unroll
        for (int tt = 0; tt < 2; ++tt) acc[b][tt] = (v4f){0.f, 0.f, 0.f, 0.f};
#pragma unroll
    for (int b = 0; b < 2; ++b) {
        v8h av = b ? aR : aC;
#pragma unroll
        for (int tt = 0; tt < 2; ++tt) {
            v8h wb = *(const v8h*)(WBh + ((b * 2 + tt) << 9) + lane * 8);
            acc[b][tt] = __builtin_amdgcn_mfma_f32_16x16x32_f16(av, wb, acc[b][tt], 0, 0, 0);
        }
    }
    float lb0c = clb[nn], lb1c = clb[16 + nn];
    float lb0r = rlb[nn], lb1r = rlb[16 + nn];
#pragma unroll
    for (int i = 0; i < 4; ++i) {
        int m = m0 + quad * 4 + i;
        float y0 = acc[0][0][i] + lb0c;
        float y1 = acc[0][1][i] + lb1c;
        out[(size_t)m * 32 + nn]      = 1.f / (1.f + __expf(-y0));
        out[(size_t)m * 32 + 16 + nn] = 1.f / (1.f + __expf(-y1));
        out[(size_t)n * 32 + (size_t)m * 32 + nn]      = acc[1][0][i] + lb0r;
        out[(size_t)n * 32 + (size_t)m * 32 + 16 + nn] = acc[1][1][i] + lb1r;
    }
}

// ---------------------------------------------------------------------------
// Aggregation (R2 core; R21 change): __launch_bounds__(256,4) lifts the VGPR
// cap to 128 so unroll 4 fits WITHOUT spilling (R7 spilled at the (256,8)
// 32-VGPR cap: +168MB scratch writes). 16 waves/CU still hide latency; each
// wave now has ~4 independent col->{es2,h} gather chains in flight.
// Math/order byte-identical to R2.
// ---------------------------------------------------------------------------
__global__ __launch_bounds__(256, 4)
void agg_kernel(const int* __restrict__ rptr,
                const int* __restrict__ col,
                const __half2* __restrict__ h,
                const float2* __restrict__ es2,
                const float2* __restrict__ ed2,
                const float* __restrict__ bc,
                const float* __restrict__ br,
                __half2* __restrict__ gout, int n) {
    int grp = (blockIdx.x * blockDim.x + threadIdx.x) >> 5;
    int lane = threadIdx.x & 31;
    int sub = lane >> 2;     // edge slot 0..7
    int fq  = lane & 3;      // feature octet 0..3
    if (grp >= n) return;
    int d = grp;
    int beg = rptr[d], end = rptr[d + 1];
    float2 edv = ed2[d];
    float accC[8], accR[8];
#pragma unroll
    for (int i = 0; i < 8; ++i) { accC[i] = 0.f; accR[i] = 0.f; }
    float lc = 0.f, lr = 0.f;
#pragma unroll 4
    for (int base = beg; base + sub < end; base += 8) {
        int e = base + sub;
        int s = ntload_i(col + e);
        float2 ev = es2[s];
        float tc = ev.x + edv.x, tr = ev.y + edv.y;
        tc = (tc > 0.f) ? tc : NEG_SLOPE * tc;
        tr = (tr > 0.f) ? tr : NEG_SLOPE * tr;
        float exc = __expf(tc), exr = __expf(tr);
        lc += exc; lr += exr;
        const uint4* rp = (const uint4*)(h + ((size_t)s << 5));
        uint4 q0 = rp[2 * fq];
        uint4 q1 = rp[2 * fq + 1];
        const __half2* hp0 = (const __half2*)&q0;
        const __half2* hp1 = (const __half2*)&q1;
#pragma unroll
        for (int i = 0; i < 4; ++i) {
            float2 v0 = __half22float2(hp0[i]);
            float2 v1 = __half22float2(hp1[i]);
            accC[i]     = fmaf(v0.x, exc, accC[i]);
            accR[i]     = fmaf(v0.y, exr, accR[i]);
            accC[4 + i] = fmaf(v1.x, exc, accC[4 + i]);
            accR[4 + i] = fmaf(v1.y, exr, accR[4 + i]);
        }
    }
#pragma unroll
    for (int off = 4; off <= 16; off <<= 1) {
        lc += __shfl_xor(lc, off, 32);
        lr += __shfl_xor(lr, off, 32);
#pragma unroll
        for (int i = 0; i < 8; ++i) {
            accC[i] += __shfl_xor(accC[i], off, 32);
            accR[i] += __shfl_xor(accR[i], off, 32);
        }
    }
    if (sub == 0) {
        float ilc = 1.f / lc, ilr = 1.f / lr;
        __half2 o[8];
#pragma unroll
        for (int i = 0; i < 8; ++i) {
            float gc = fmaxf(accC[i] * ilc + bc[fq * 8 + i], 0.f);
            float gr = fmaxf(accR[i] * ilr + br[fq * 8 + i], 0.f);
            o[i] = __floats2half2_rn(gc, gr);
        }
        uint4* dst = (uint4*)(gout + ((size_t)d << 5) + fq * 8);
        dst[0] = *(const uint4*)&o[0];
        dst[1] = *(const uint4*)&o[4];
    }
}

// ---------------------------------------------------------------------------
// Launch
// ---------------------------------------------------------------------------
extern "C" void kernel_launch(void* const* d_in, const int* in_sizes, int n_in,
                              void* d_out, int out_size, void* d_ws, size_t ws_size,
                              hipStream_t stream) {
    const float* x = (const float*)d_in[0];
    const int* ei = (const int*)d_in[1];   // int32; [src(E), dst(E)]
    const int N = in_sizes[0] / 64;
    const int E = in_sizes[1] / 2;
    const int Etot = E + N;

    const float* cW1  = (const float*)d_in[2];
    const float* cas1 = (const float*)d_in[3];
    const float* cad1 = (const float*)d_in[4];
    const float* cb1  = (const float*)d_in[5];
    const float* cW2  = (const float*)d_in[6];
    const float* cas2 = (const float*)d_in[7];
    const float* cad2 = (const float*)d_in[8];
    const float* cb2  = (const float*)d_in[9];
    const float* clW  = (const float*)d_in[10];
    const float* clb  = (const float*)d_in[11];
    const float* rW1  = (const float*)d_in[12];
    const float* ras1 = (const float*)d_in[13];
    const float* rad1 = (const float*)d_in[14];
    const float* rb1  = (const float*)d_in[15];
    const float* rW2  = (const float*)d_in[16];
    const float* ras2 = (const float*)d_in[17];
    const float* rad2 = (const float*)d_in[18];
    const float* rb2  = (const float*)d_in[19];
    const float* rlW  = (const float*)d_in[20];
    const float* rlb  = (const float*)d_in[21];

    const int nbuck = (N + DSZ - 1) >> DSHIFT;   // 391 for N=50000 (<=512)

    char* w = (char*)d_ws;
    size_t off = 0;
    auto alloc = [&](size_t bytes) {
        void* p = w + off;
        off = (off + bytes + 255) & ~(size_t)255;
        return p;
    };
    int*       rptr    = (int*)alloc((size_t)(N + 1) * 4);
    int*       bcount  = (int*)alloc(NBUCK_MAX * 4);
    int*       colbase = (int*)alloc(NBUCK_MAX * 4);
    int*       pcur    = (int*)alloc(NBUCK_MAX * 4);
    int*       col     = (int*)alloc((size_t)Etot * 4);
    unsigned*  pairs   = (unsigned*)alloc((size_t)Etot * 4);   // 6.8 MB packed
    __half2*   h       = (__half2*)alloc((size_t)N * 32 * 4);  // h1, reused as h2
    __half2*   g       = (__half2*)alloc((size_t)N * 32 * 4);  // g1, reused as g2
    float2*    esA     = (float2*)alloc((size_t)N * 8);
    float2*    edA     = (float2*)alloc((size_t)N * 8);
    float2*    esB     = (float2*)alloc((size_t)N * 8);
    float2*    edB     = (float2*)alloc((size_t)N * 8);
    _Float16*  xh      = (_Float16*)alloc((size_t)N * 64 * 2); // 6.4 MB
    _Float16*  WB1     = (_Float16*)alloc(6144 * 2);
    _Float16*  WB2     = (_Float16*)alloc(3072 * 2);
    _Float16*  WBh     = (_Float16*)alloc(2048 * 2);
    (void)ws_size;

    float* out = (float*)d_out;
    const int node_blocks = (N * 32 + 255) / 256;   // 32-lane groups (agg)
    const int xc_blocks   = (N * 64 / 4 + 255) / 256;
    const int mfma_blocks = ((N >> 4) * 64 + 255) / 256;  // 1 wave / 16 nodes

    // ---- MFMA prep + CSR build ----
    xcast_kernel<<<xc_blocks, 256, 0, stream>>>(x, xh, N * 64 / 4, bcount);
    prep_kernel<<<1, 256, 0, stream>>>(cW1, rW1, cas1, cad1, ras1, rad1,
                                       cW2, rW2, cas2, cad2, ras2, rad2,
                                       clW, rlW, WB1, WB2, WBh);
    part_count_kernel<<<PART_BLOCKS, 256, 0, stream>>>(ei, E, N, nbuck, bcount);
    bucket_scan_kernel<<<1, 512, 0, stream>>>(bcount, colbase, pcur, rptr, N, nbuck);
    part_write_kernel<<<PART_BLOCKS, 256, 0, stream>>>(ei, E, N, nbuck, pcur, pairs);
    fine_kernel<<<nbuck, 256, 0, stream>>>(pairs, colbase, bcount, rptr, col, N);

    // ---- layer 1 ----
    t1_mfma_kernel<<<mfma_blocks, 256, 0, stream>>>(xh, WB1, h, esA, edA, N);
    agg_kernel<<<node_blocks, 256, 0, stream>>>(
        rptr, col, h, esA, edA, cb1, rb1, g, N);

    // ---- layer 2 + heads ----
    t2_mfma_kernel<<<mfma_blocks, 256, 0, stream>>>(g, WB2, h, esB, edB, N);
    agg_kernel<<<node_blocks, 256, 0, stream>>>(
        rptr, col, h, esB, edB, cb2, rb2, g, N);
    head_mfma_kernel<<<mfma_blocks, 256, 0, stream>>>(g, WBh, clb, rlb, out, N);
}

// Round 9
// 278.441 us; speedup vs baseline: 1.5271x; 1.0387x over previous
//
#include <hip/hip_runtime.h>
#include <hip/hip_fp16.h>
#include <math.h>

#define NEG_SLOPE 0.2f

// ---- bucket CSR parameters: 128-node buckets (s packs in 16b since N<65536,
//      dlocal in 7b -> 4-byte pair entries) ----
#define DSHIFT 7
#define DSZ 128
#define NBUCK_MAX 512
#define PART_BLOCKS 256

typedef __attribute__((ext_vector_type(8))) _Float16 v8h;
typedef __attribute__((ext_vector_type(4))) float v4f;

__device__ __forceinline__ int ntload_i(const int* p) {
    return __builtin_nontemporal_load(p);
}

// ---------------------------------------------------------------------------
// prep: zero bcount (replay safety; runs first, stream-ordered) + build
// B-fragments for all three MFMA transforms.
// ---------------------------------------------------------------------------
__global__ void prep_kernel(const float* __restrict__ cW1, const float* __restrict__ rW1,
                            const float* __restrict__ cas1, const float* __restrict__ cad1,
                            const float* __restrict__ ras1, const float* __restrict__ rad1,
                            const float* __restrict__ cW2, const float* __restrict__ rW2,
                            const float* __restrict__ cas2, const float* __restrict__ cad2,
                            const float* __restrict__ ras2, const float* __restrict__ rad2,
                            const float* __restrict__ clW, const float* __restrict__ rlW,
                            _Float16* __restrict__ WB1,
                            _Float16* __restrict__ WB2,
                            _Float16* __restrict__ WBh,
                            int* __restrict__ bcount) {
    __shared__ float f1s[2][64], f1d[2][64];
    __shared__ float f2s[2][32], f2d[2][32];
    int t = threadIdx.x;
    bcount[t] = 0;
    bcount[t + 256] = 0;
    if (t < 128) {
        int b = t >> 6, k = t & 63;
        const float* W   = b ? rW1 : cW1;
        const float* as_ = b ? ras1 : cas1;
        const float* ad_ = b ? rad1 : cad1;
        float s1 = 0.f, s2 = 0.f;
        for (int f = 0; f < 32; ++f) {
            s1 = fmaf(W[k * 32 + f], as_[f], s1);
            s2 = fmaf(W[k * 32 + f], ad_[f], s2);
        }
        f1s[b][k] = s1;
        f1d[b][k] = s2;
    } else if (t < 192) {
        int b = (t - 128) >> 5, k = (t - 128) & 31;
        const float* W   = b ? rW2 : cW2;
        const float* as_ = b ? ras2 : cas2;
        const float* ad_ = b ? rad2 : cad2;
        float s1 = 0.f, s2 = 0.f;
        for (int f = 0; f < 32; ++f) {
            s1 = fmaf(W[k * 32 + f], as_[f], s1);
            s2 = fmaf(W[k * 32 + f], ad_[f], s2);
        }
        f2s[b][k] = s1;
        f2d[b][k] = s2;
    }
    __syncthreads();
    for (int idx = t; idx < 6144; idx += 256) {   // WB1
        int blk = idx >> 9;
        int l = (idx >> 3) & 63, j = idx & 7;
        int b = blk / 6, rem = blk % 6, c = rem / 3, tt = rem % 3;
        int k = c * 32 + (l >> 4) * 8 + j;
        int nn = l & 15;
        const float* W = b ? rW1 : cW1;
        float v;
        if (tt < 2) v = W[k * 32 + tt * 16 + nn];
        else v = (nn == 0) ? f1s[b][k] : ((nn == 1) ? f1d[b][k] : 0.f);
        WB1[idx] = (_Float16)v;
    }
    for (int idx = t; idx < 3072; idx += 256) {   // WB2
        int blk = idx >> 9;
        int l = (idx >> 3) & 63, j = idx & 7;
        int b = blk / 3, tt = blk % 3;
        int k = (l >> 4) * 8 + j;
        int nn = l & 15;
        const float* W = b ? rW2 : cW2;
        float v;
        if (tt < 2) v = W[k * 32 + tt * 16 + nn];
        else v = (nn == 0) ? f2s[b][k] : ((nn == 1) ? f2d[b][k] : 0.f);
        WB2[idx] = (_Float16)v;
    }
    for (int idx = t; idx < 2048; idx += 256) {   // WBh
        int blk = idx >> 9;
        int l = (idx >> 3) & 63, j = idx & 7;
        int b = blk >> 1, tt = blk & 1;
        int k = (l >> 4) * 8 + j;
        int nn = l & 15;
        const float* W = b ? rlW : clW;
        WBh[idx] = (_Float16)W[k * 32 + tt * 16 + nn];
    }
}

// ---------------------------------------------------------------------------
// Fused t1 + part_count (R22): blocks [0, t1b) do the layer-1 MFMA transform
// reading x fp32 directly (xcast deleted; identical (_Float16) conversion in
// register). Blocks [t1b, t1b+PART_BLOCKS) do the CSR bucket histogram.
// The two are independent (both depend only on prep); fusing overlaps the
// E-scan under the MFMA work instead of serializing two dispatches.
// ---------------------------------------------------------------------------
__global__ __launch_bounds__(256)
void t1pc_kernel(const float* __restrict__ x,
                 const _Float16* __restrict__ WB1,
                 __half2* __restrict__ h,
                 float2* __restrict__ es2,
                 float2* __restrict__ ed2, int n,
                 const int* __restrict__ ei, int E, int nbuck,
                 int* __restrict__ bcount, int t1b) {
    __shared__ int cnt[NBUCK_MAX];
    if ((int)blockIdx.x >= t1b) {
        // ---- part_count path ----
        int b = blockIdx.x - t1b;
        int t = threadIdx.x;
        for (int k = t; k < nbuck; k += 256) cnt[k] = 0;
        __syncthreads();
        int Etot = E + n;
        int chunk = (Etot + PART_BLOCKS - 1) / PART_BLOCKS;
        int s0 = b * chunk;
        int s1 = min(Etot, s0 + chunk);
        for (int i = s0 + t; i < s1; i += 256) {
            int d = (i < E) ? ntload_i(ei + E + i) : (i - E);
            if ((unsigned)d < (unsigned)n) atomicAdd(&cnt[d >> DSHIFT], 1);
        }
        __syncthreads();
        for (int k = t; k < nbuck; k += 256) {
            int c = cnt[k];
            if (c) atomicAdd(&bcount[k], c);
        }
        return;
    }
    // ---- t1 path ----
    int wave = (blockIdx.x * blockDim.x + threadIdx.x) >> 6;
    int lane = threadIdx.x & 63;
    int ntiles = n >> 4;
    if (wave >= ntiles) return;
    int m0 = wave << 4;
    int quad = lane >> 4, nn = lane & 15;
    const float* xrow = x + (size_t)(m0 + nn) * 64 + quad * 8;
    float4 f0 = *(const float4*)xrow;
    float4 f1 = *(const float4*)(xrow + 4);
    float4 f2 = *(const float4*)(xrow + 32);
    float4 f3 = *(const float4*)(xrow + 36);
    v8h a0, a1;
    a0[0] = (_Float16)f0.x; a0[1] = (_Float16)f0.y;
    a0[2] = (_Float16)f0.z; a0[3] = (_Float16)f0.w;
    a0[4] = (_Float16)f1.x; a0[5] = (_Float16)f1.y;
    a0[6] = (_Float16)f1.z; a0[7] = (_Float16)f1.w;
    a1[0] = (_Float16)f2.x; a1[1] = (_Float16)f2.y;
    a1[2] = (_Float16)f2.z; a1[3] = (_Float16)f2.w;
    a1[4] = (_Float16)f3.x; a1[5] = (_Float16)f3.y;
    a1[6] = (_Float16)f3.z; a1[7] = (_Float16)f3.w;
    v4f acc[2][3];
#pragma unroll
    for (int b = 0; b < 2; ++b)
#pragma unroll
        for (int tt = 0; tt < 3; ++tt) acc[b][tt] = (v4f){0.f, 0.f, 0.f, 0.f};
#pragma unroll
    for (int b = 0; b < 2; ++b) {
#pragma unroll
        for (int c = 0; c < 2; ++c) {
            v8h av = c ? a1 : a0;
#pragma unroll
            for (int tt = 0; tt < 3; ++tt) {
                v8h wb = *(const v8h*)(WB1 + (((b * 2 + c) * 3 + tt) << 9) + lane * 8);
                acc[b][tt] = __builtin_amdgcn_mfma_f32_16x16x32_f16(av, wb, acc[b][tt], 0, 0, 0);
            }
        }
    }
#pragma unroll
    for (int i = 0; i < 4; ++i) {
        int m = m0 + quad * 4 + i;
        h[(size_t)m * 32 + nn]      = __floats2half2_rn(acc[0][0][i], acc[1][0][i]);
        h[(size_t)m * 32 + 16 + nn] = __floats2half2_rn(acc[0][1][i], acc[1][1][i]);
        if (nn == 0) es2[m] = make_float2(acc[0][2][i], acc[1][2][i]);
        if (nn == 1) ed2[m] = make_float2(acc[0][2][i], acc[1][2][i]);
    }
}

// ---------------------------------------------------------------------------
// CSR build (R16 structure, proven at 278.8): scan, pair write, fine sort.
// ---------------------------------------------------------------------------
__global__ void bucket_scan_kernel(const int* __restrict__ bcount,
                                   int* __restrict__ colbase,
                                   int* __restrict__ pcur,
                                   int* __restrict__ rptr,
                                   int n, int nbuck) {
    __shared__ int sm[512];
    int t = threadIdx.x;
    int v = (t < nbuck) ? bcount[t] : 0;
    sm[t] = v;
    __syncthreads();
    int x = v;
    for (int off = 1; off < 512; off <<= 1) {
        int y = (t >= off) ? sm[t - off] : 0;
        __syncthreads();
        x += y;
        sm[t] = x;
        __syncthreads();
    }
    if (t < nbuck) { colbase[t] = x - v; pcur[t] = x - v; }
    if (t == nbuck - 1) rptr[n] = x;
}

__global__ __launch_bounds__(256)
void part_write_kernel(const int* __restrict__ ei, int E, int n, int nbuck,
                       int* __restrict__ pcur,
                       unsigned* __restrict__ pairs) {
    __shared__ int cnt[NBUCK_MAX];
    __shared__ int lcur[NBUCK_MAX];
    int t = threadIdx.x;
    for (int k = t; k < nbuck; k += 256) cnt[k] = 0;
    __syncthreads();
    int Etot = E + n;
    int chunk = (Etot + gridDim.x - 1) / gridDim.x;
    int s0 = blockIdx.x * chunk;
    int s1 = min(Etot, s0 + chunk);
    for (int i = s0 + t; i < s1; i += 256) {
        int d = (i < E) ? ntload_i(ei + E + i) : (i - E);
        if ((unsigned)d < (unsigned)n) atomicAdd(&cnt[d >> DSHIFT], 1);
    }
    __syncthreads();
    for (int k = t; k < nbuck; k += 256) {
        int c = cnt[k];
        if (c) lcur[k] = atomicAdd(&pcur[k], c);
    }
    __syncthreads();
    for (int i = s0 + t; i < s1; i += 256) {
        int s, d;
        if (i < E) { s = ntload_i(ei + i); d = ntload_i(ei + E + i); }
        else       { s = d = i - E; }
        if ((unsigned)d < (unsigned)n) {
            if ((unsigned)s >= (unsigned)n) s = 0;   // defensive clamp
            int pos = atomicAdd(&lcur[d >> DSHIFT], 1);
            pairs[pos] = (unsigned)s | ((unsigned)(d & (DSZ - 1)) << 16);
        }
    }
}

__global__ __launch_bounds__(256)
void fine_kernel(const unsigned* __restrict__ pairs,
                 const int* __restrict__ colbase,
                 const int* __restrict__ bcount,
                 int* __restrict__ rptr,
                 int* __restrict__ col, int n) {
    __shared__ int cnt[DSZ];
    __shared__ int ofs[DSZ];
    int b = blockIdx.x, t = threadIdx.x;
    int p0 = colbase[b], p1 = p0 + bcount[b];
    if (t < DSZ) cnt[t] = 0;
    __syncthreads();
    for (int i = p0 + t; i < p1; i += 256)
        atomicAdd(&cnt[pairs[i] >> 16], 1);
    __syncthreads();
    int v = (t < DSZ) ? cnt[t] : 0;
    if (t < DSZ) ofs[t] = v;
    __syncthreads();
    int x = v;
    for (int off = 1; off < DSZ; off <<= 1) {
        int y = (t >= off && t < DSZ) ? ofs[t - off] : 0;
        __syncthreads();
        if (t < DSZ) { x += y; ofs[t] = x; }
        __syncthreads();
    }
    int d0 = b << DSHIFT;
    if (t < DSZ) {
        int start = p0 + x - v;
        if (d0 + t < n) rptr[d0 + t] = start;
        cnt[t] = start;   // reuse as cursor
    }
    __syncthreads();
    for (int i = p0 + t; i < p1; i += 256) {
        unsigned u = pairs[i];
        int pos = atomicAdd(&cnt[u >> 16], 1);
        col[pos] = (int)(u & 0xFFFFu);
    }
}

// ---------------------------------------------------------------------------
// A-fragment builder from fused half2 rows (proven).
// ---------------------------------------------------------------------------
__device__ __forceinline__ void load_a_frag(const __half2* __restrict__ g,
                                            int m0, int nn, int quad,
                                            v8h& aC, v8h& aR) {
    const uint4* gp = (const uint4*)(g + (size_t)(m0 + nn) * 32 + quad * 8);
    uint4 q0 = gp[0], q1 = gp[1];
    unsigned short buf[16];
    *(uint4*)buf = q0;
    *(uint4*)(buf + 8) = q1;
#pragma unroll
    for (int i = 0; i < 8; ++i) {
        ((unsigned short*)&aC)[i] = buf[2 * i];
        ((unsigned short*)&aR)[i] = buf[2 * i + 1];
    }
}

// ---------------------------------------------------------------------------
// t2 via MFMA (proven).
// ---------------------------------------------------------------------------
__global__ __launch_bounds__(256)
void t2_mfma_kernel(const __half2* __restrict__ g1,
                    const _Float16* __restrict__ WB2,
                    __half2* __restrict__ h2,
                    float2* __restrict__ es2o,
                    float2* __restrict__ ed2o, int n) {
    int wave = (blockIdx.x * blockDim.x + threadIdx.x) >> 6;
    int lane = threadIdx.x & 63;
    if (wave >= (n >> 4)) return;
    int m0 = wave << 4;
    int quad = lane >> 4, nn = lane & 15;
    v8h aC, aR;
    load_a_frag(g1, m0, nn, quad, aC, aR);
    v4f acc[2][3];
#pragma unroll
    for (int b = 0; b < 2; ++b)
#pragma unroll
        for (int tt = 0; tt < 3; ++tt) acc[b][tt] = (v4f){0.f, 0.f, 0.f, 0.f};
#pragma unroll
    for (int b = 0; b < 2; ++b) {
        v8h av = b ? aR : aC;
#pragma unroll
        for (int tt = 0; tt < 3; ++tt) {
            v8h wb = *(const v8h*)(WB2 + ((b * 3 + tt) << 9) + lane * 8);
            acc[b][tt] = __builtin_amdgcn_mfma_f32_16x16x32_f16(av, wb, acc[b][tt], 0, 0, 0);
        }
    }
#pragma unroll
    for (int i = 0; i < 4; ++i) {
        int m = m0 + quad * 4 + i;
        h2[(size_t)m * 32 + nn]      = __floats2half2_rn(acc[0][0][i], acc[1][0][i]);
        h2[(size_t)m * 32 + 16 + nn] = __floats2half2_rn(acc[0][1][i], acc[1][1][i]);
        if (nn == 0) es2o[m] = make_float2(acc[0][2][i], acc[1][2][i]);
        if (nn == 1) ed2o[m] = make_float2(acc[0][2][i], acc[1][2][i]);
    }
}

// ---------------------------------------------------------------------------
// head via MFMA (proven).
// ---------------------------------------------------------------------------
__global__ __launch_bounds__(256)
void head_mfma_kernel(const __half2* __restrict__ g2,
                      const _Float16* __restrict__ WBh,
                      const float* __restrict__ clb,
                      const float* __restrict__ rlb,
                      float* __restrict__ out, int n) {
    int wave = (blockIdx.x * blockDim.x + threadIdx.x) >> 6;
    int lane = threadIdx.x & 63;
    if (wave >= (n >> 4)) return;
    int m0 = wave << 4;
    int quad = lane >> 4, nn = lane & 15;
    v8h aC, aR;
    load_a_frag(g2, m0, nn, quad, aC, aR);
    v4f acc[2][2];
#pragma unroll
    for (int b = 0; b < 2; ++b)
#pragma unroll
        for (int tt = 0; tt < 2; ++tt) acc[b][tt] = (v4f){0.f, 0.f, 0.f, 0.f};
#pragma unroll
    for (int b = 0; b < 2; ++b) {
        v8h av = b ? aR : aC;
#pragma unroll
        for (int tt = 0; tt < 2; ++tt) {
            v8h wb = *(const v8h*)(WBh + ((b * 2 + tt) << 9) + lane * 8);
            acc[b][tt] = __builtin_amdgcn_mfma_f32_16x16x32_f16(av, wb, acc[b][tt], 0, 0, 0);
        }
    }
    float lb0c = clb[nn], lb1c = clb[16 + nn];
    float lb0r = rlb[nn], lb1r = rlb[16 + nn];
#pragma unroll
    for (int i = 0; i < 4; ++i) {
        int m = m0 + quad * 4 + i;
        float y0 = acc[0][0][i] + lb0c;
        float y1 = acc[0][1][i] + lb1c;
        out[(size_t)m * 32 + nn]      = 1.f / (1.f + __expf(-y0));
        out[(size_t)m * 32 + 16 + nn] = 1.f / (1.f + __expf(-y1));
        out[(size_t)n * 32 + (size_t)m * 32 + nn]      = acc[1][0][i] + lb0r;
        out[(size_t)n * 32 + (size_t)m * 32 + 16 + nn] = acc[1][1][i] + lb1r;
    }
}

// ---------------------------------------------------------------------------
// Aggregation — EXACT R2 core (best measured: <43.5us/dispatch, 278.8 total).
// (256,8), unroll 2, interleaved h gathers. R7 (spill) and R8 (occupancy
// trade) both refuted deviations; this is the measured floor config.
// ---------------------------------------------------------------------------
__global__ __launch_bounds__(256, 8)
void agg_kernel(const int* __restrict__ rptr,
                const int* __restrict__ col,
                const __half2* __restrict__ h,
                const float2* __restrict__ es2,
                const float2* __restrict__ ed2,
                const float* __restrict__ bc,
                const float* __restrict__ br,
                __half2* __restrict__ gout, int n) {
    int grp = (blockIdx.x * blockDim.x + threadIdx.x) >> 5;
    int lane = threadIdx.x & 31;
    int sub = lane >> 2;     // edge slot 0..7
    int fq  = lane & 3;      // feature octet 0..3
    if (grp >= n) return;
    int d = grp;
    int beg = rptr[d], end = rptr[d + 1];
    float2 edv = ed2[d];
    float accC[8], accR[8];
#pragma unroll
    for (int i = 0; i < 8; ++i) { accC[i] = 0.f; accR[i] = 0.f; }
    float lc = 0.f, lr = 0.f;
#pragma unroll 2
    for (int base = beg; base + sub < end; base += 8) {
        int e = base + sub;
        int s = ntload_i(col + e);
        float2 ev = es2[s];
        float tc = ev.x + edv.x, tr = ev.y + edv.y;
        tc = (tc > 0.f) ? tc : NEG_SLOPE * tc;
        tr = (tr > 0.f) ? tr : NEG_SLOPE * tr;
        float exc = __expf(tc), exr = __expf(tr);
        lc += exc; lr += exr;
        const uint4* rp = (const uint4*)(h + ((size_t)s << 5));
        uint4 q0 = rp[2 * fq];
        uint4 q1 = rp[2 * fq + 1];
        const __half2* hp0 = (const __half2*)&q0;
        const __half2* hp1 = (const __half2*)&q1;
#pragma unroll
        for (int i = 0; i < 4; ++i) {
            float2 v0 = __half22float2(hp0[i]);
            float2 v1 = __half22float2(hp1[i]);
            accC[i]     = fmaf(v0.x, exc, accC[i]);
            accR[i]     = fmaf(v0.y, exr, accR[i]);
            accC[4 + i] = fmaf(v1.x, exc, accC[4 + i]);
            accR[4 + i] = fmaf(v1.y, exr, accR[4 + i]);
        }
    }
#pragma unroll
    for (int off = 4; off <= 16; off <<= 1) {
        lc += __shfl_xor(lc, off, 32);
        lr += __shfl_xor(lr, off, 32);
#pragma unroll
        for (int i = 0; i < 8; ++i) {
            accC[i] += __shfl_xor(accC[i], off, 32);
            accR[i] += __shfl_xor(accR[i], off, 32);
        }
    }
    if (sub == 0) {
        float ilc = 1.f / lc, ilr = 1.f / lr;
        __half2 o[8];
#pragma unroll
        for (int i = 0; i < 8; ++i) {
            float gc = fmaxf(accC[i] * ilc + bc[fq * 8 + i], 0.f);
            float gr = fmaxf(accR[i] * ilr + br[fq * 8 + i], 0.f);
            o[i] = __floats2half2_rn(gc, gr);
        }
        uint4* dst = (uint4*)(gout + ((size_t)d << 5) + fq * 8);
        dst[0] = *(const uint4*)&o[0];
        dst[1] = *(const uint4*)&o[4];
    }
}

// ---------------------------------------------------------------------------
// Launch
// ---------------------------------------------------------------------------
extern "C" void kernel_launch(void* const* d_in, const int* in_sizes, int n_in,
                              void* d_out, int out_size, void* d_ws, size_t ws_size,
                              hipStream_t stream) {
    const float* x = (const float*)d_in[0];
    const int* ei = (const int*)d_in[1];   // int32; [src(E), dst(E)]
    const int N = in_sizes[0] / 64;
    const int E = in_sizes[1] / 2;
    const int Etot = E + N;

    const float* cW1  = (const float*)d_in[2];
    const float* cas1 = (const float*)d_in[3];
    const float* cad1 = (const float*)d_in[4];
    const float* cb1  = (const float*)d_in[5];
    const float* cW2  = (const float*)d_in[6];
    const float* cas2 = (const float*)d_in[7];
    const float* cad2 = (const float*)d_in[8];
    const float* cb2  = (const float*)d_in[9];
    const float* clW  = (const float*)d_in[10];
    const float* clb  = (const float*)d_in[11];
    const float* rW1  = (const float*)d_in[12];
    const float* ras1 = (const float*)d_in[13];
    const float* rad1 = (const float*)d_in[14];
    const float* rb1  = (const float*)d_in[15];
    const float* rW2  = (const float*)d_in[16];
    const float* ras2 = (const float*)d_in[17];
    const float* rad2 = (const float*)d_in[18];
    const float* rb2  = (const float*)d_in[19];
    const float* rlW  = (const float*)d_in[20];
    const float* rlb  = (const float*)d_in[21];

    const int nbuck = (N + DSZ - 1) >> DSHIFT;   // 391 for N=50000 (<=512)

    char* w = (char*)d_ws;
    size_t off = 0;
    auto alloc = [&](size_t bytes) {
        void* p = w + off;
        off = (off + bytes + 255) & ~(size_t)255;
        return p;
    };
    int*       rptr    = (int*)alloc((size_t)(N + 1) * 4);
    int*       bcount  = (int*)alloc(NBUCK_MAX * 4);
    int*       colbase = (int*)alloc(NBUCK_MAX * 4);
    int*       pcur    = (int*)alloc(NBUCK_MAX * 4);
    int*       col     = (int*)alloc((size_t)Etot * 4);
    unsigned*  pairs   = (unsigned*)alloc((size_t)Etot * 4);   // 6.8 MB packed
    __half2*   h       = (__half2*)alloc((size_t)N * 32 * 4);  // h1, reused as h2
    __half2*   g       = (__half2*)alloc((size_t)N * 32 * 4);  // g1, reused as g2
    float2*    esA     = (float2*)alloc((size_t)N * 8);
    float2*    edA     = (float2*)alloc((size_t)N * 8);
    float2*    esB     = (float2*)alloc((size_t)N * 8);
    float2*    edB     = (float2*)alloc((size_t)N * 8);
    _Float16*  WB1     = (_Float16*)alloc(6144 * 2);
    _Float16*  WB2     = (_Float16*)alloc(3072 * 2);
    _Float16*  WBh     = (_Float16*)alloc(2048 * 2);
    (void)ws_size;

    float* out = (float*)d_out;
    const int node_blocks = (N * 32 + 255) / 256;   // 32-lane groups (agg)
    const int mfma_blocks = ((N >> 4) * 64 + 255) / 256;  // 1 wave / 16 nodes

    // ---- prep (zeroes bcount) -> fused t1+count -> CSR chain ----
    prep_kernel<<<1, 256, 0, stream>>>(cW1, rW1, cas1, cad1, ras1, rad1,
                                       cW2, rW2, cas2, cad2, ras2, rad2,
                                       clW, rlW, WB1, WB2, WBh, bcount);
    t1pc_kernel<<<mfma_blocks + PART_BLOCKS, 256, 0, stream>>>(
        x, WB1, h, esA, edA, N, ei, E, nbuck, bcount, mfma_blocks);
    bucket_scan_kernel<<<1, 512, 0, stream>>>(bcount, colbase, pcur, rptr, N, nbuck);
    part_write_kernel<<<PART_BLOCKS, 256, 0, stream>>>(ei, E, N, nbuck, pcur, pairs);
    fine_kernel<<<nbuck, 256, 0, stream>>>(pairs, colbase, bcount, rptr, col, N);

    // ---- layer 1 aggregation ----
    agg_kernel<<<node_blocks, 256, 0, stream>>>(
        rptr, col, h, esA, edA, cb1, rb1, g, N);

    // ---- layer 2 + heads ----
    t2_mfma_kernel<<<mfma_blocks, 256, 0, stream>>>(g, WB2, h, esB, edB, N);
    agg_kernel<<<node_blocks, 256, 0, stream>>>(
        rptr, col, h, esB, edB, cb2, rb2, g, N);
    head_mfma_kernel<<<mfma_blocks, 256, 0, stream>>>(g, WBh, clb, rlb, out, N);
}